// Round 1
// 149.760 us; speedup vs baseline: 1.0497x; 1.0497x over previous
//
#include <hip/hip_runtime.h>
#include <math.h>

// Problem constants (from reference setup_inputs)
#define BS 4
#define C  3
#define D  8
#define K  10
#define K1 11
#define H  128
#define W  128
#define HW (H*W)

// 4-byte-aligned float4 for unaligned-window vector loads (window start is
// wi0 + sx with sx arbitrary, so only dword alignment is guaranteed).
typedef float float4a __attribute__((ext_vector_type(4), aligned(4)));

// Kernel 1: per-(b,d,k) heatmap normalization constant (separable row/col sums).
// One 64-thread wave per (b,d,k); writes 1/sum to norm[].
__global__ void memb_norm_kernel(const float* __restrict__ kpd,
                                 float* __restrict__ norm) {
    int idx = blockIdx.x;              // 0 .. BS*D*K-1
    float kx = kpd[idx * 2 + 0];
    float ky = kpd[idx * 2 + 1];
    int lane = threadIdx.x;            // 0..63, one wave
    float sx = 0.f, sy = 0.f;
    #pragma unroll
    for (int j = lane; j < W; j += 64) {
        float coord = (float)j * (2.0f / 127.0f) - 1.0f;
        float ddx = coord - kx;
        float ddy = coord - ky;
        sx += __expf(-50.0f * ddx * ddx);
        sy += __expf(-50.0f * ddy * ddy);
    }
    #pragma unroll
    for (int o = 32; o > 0; o >>= 1) {
        sx += __shfl_down(sx, o, 64);
        sy += __shfl_down(sy, o, 64);
    }
    if (lane == 0) norm[idx] = 1.0f / (sx * sy);
}

// Kernel 2: one thread per 4 consecutive pixels of one (b,d,k) slot.
// blockIdx.y = (b*D+di)*K1 + k  → all kp data is block-uniform (scalar).
// Key fact: px = (x + dx + 1)*63.5 = wi + 63.5*dx, so the bilinear fractional
// weights and integer shift are UNIFORM per slot — the gather is a shifted
// 2-row window blend, vectorizable with dwordx4 loads and float4 stores.
__global__ void memb_main_kernel(const float* __restrict__ src,
                                 const float* __restrict__ kpd,
                                 const float* __restrict__ kps,
                                 const float* __restrict__ norm,
                                 float* __restrict__ out) {
    int rk = blockIdx.y;               // 0 .. BS*D*K1-1
    int k  = rk % K1;
    int r  = rk / K1;                  // b*D + di
    int di = r & (D - 1);
    int b  = r >> 3;

    float kx = 0.f, ky = 0.f, dx = 0.f, dy = 0.f, nrm = 0.f;
    if (k > 0) {
        int kidx = r * K + (k - 1);
        kx  = kpd[kidx * 2 + 0];
        ky  = kpd[kidx * 2 + 1];
        dx  = kps[kidx * 2 + 0] - kx;
        dy  = kps[kidx * 2 + 1] - ky;
        nrm = norm[kidx];              // k==0: nrm=0 → heat=0, dx=dy=0 → identity copy
    }

    int p   = (blockIdx.x * blockDim.x + threadIdx.x) << 2;  // pixel base, 0..16380
    int wi0 = p & (W - 1);             // multiple of 4 → 16B-aligned stores
    int hi  = p >> 7;

    // Gaussian heatmap, separable: exp(-50*(ex^2+ey^2)) = expx * expy
    float y  = (float)hi * (2.0f / 127.0f) - 1.0f;
    float ey = y - ky;
    float expy = __expf(-50.0f * ey * ey) * nrm;
    float heat[4];
    #pragma unroll
    for (int j = 0; j < 4; j++) {
        float x  = (float)(wi0 + j) * (2.0f / 127.0f) - 1.0f;
        float ex = x - kx;
        heat[j] = expy * __expf(-50.0f * ex * ex);
    }

    // Uniform bilinear shift + weights for this slot.
    float cx = 63.5f * dx, cy = 63.5f * dy;
    float fsx = floorf(cx), fsy = floorf(cy);
    float fx = cx - fsx,    fy = cy - fsy;
    int   sx = (int)fsx,    sy = (int)fsy;
    float wx0 = 1.0f - fx,  wx1 = fx;

    int iy0 = hi + sy, iy1 = iy0 + 1;
    float rv0 = (iy0 >= 0 && iy0 < H) ? (1.0f - fy) : 0.0f;  // wy0 * y-valid
    float rv1 = (iy1 >= 0 && iy1 < H) ? fy : 0.0f;           // wy1 * y-valid
    int cy0 = min(max(iy0, 0), H - 1);
    int cy1 = min(max(iy1, 0), H - 1);

    int c0 = wi0 + sx;                 // leftmost source column needed (of 5)
    const float* sb = src + (size_t)b * C * HW;

    float v[C][4];
    if (c0 >= 0 && c0 <= W - 5) {
        // Fast path: whole 5-column window in range → vector loads, no masks.
        #pragma unroll
        for (int ci = 0; ci < C; ci++) {
            const float* r0 = sb + ci * HW + cy0 * W;
            const float* r1 = sb + ci * HW + cy1 * W;
            float4a a  = *(const float4a*)(r0 + c0);
            float   a4 = r0[c0 + 4];
            float4a bq = *(const float4a*)(r1 + c0);
            float   b4 = r1[c0 + 4];
            float m0 = rv0 * a[0] + rv1 * bq[0];
            float m1 = rv0 * a[1] + rv1 * bq[1];
            float m2 = rv0 * a[2] + rv1 * bq[2];
            float m3 = rv0 * a[3] + rv1 * bq[3];
            float m4 = rv0 * a4   + rv1 * b4;
            v[ci][0] = wx0 * m0 + wx1 * m1;
            v[ci][1] = wx0 * m1 + wx1 * m2;
            v[ci][2] = wx0 * m2 + wx1 * m3;
            v[ci][3] = wx0 * m3 + wx1 * m4;
        }
    } else {
        // Edge path: clamped addresses + multiplicative masks (branch-free body).
        #pragma unroll
        for (int ci = 0; ci < C; ci++) {
            const float* r0 = sb + ci * HW + cy0 * W;
            const float* r1 = sb + ci * HW + cy1 * W;
            float m[5];
            #pragma unroll
            for (int i = 0; i < 5; i++) {
                int q = c0 + i;
                bool ok = (q >= 0) && (q < W);
                int qc = min(max(q, 0), W - 1);
                float mm = rv0 * r0[qc] + rv1 * r1[qc];
                m[i] = ok ? mm : 0.0f;
            }
            v[ci][0] = wx0 * m[0] + wx1 * m[1];
            v[ci][1] = wx0 * m[1] + wx1 * m[2];
            v[ci][2] = wx0 * m[2] + wx1 * m[3];
            v[ci][3] = wx0 * m[3] + wx1 * m[4];
        }
    }

    // out flat index: ((b*66 + k*6 + j)*D + di)*HW + hi*W + wi0 ; float4 stores.
    const size_t cs = (size_t)D * HW;
    size_t base = ((size_t)(b * 66 + k * 6) * D + di) * HW + (size_t)hi * W + wi0;
    *(float4*)(out + base + 0 * cs) = make_float4(heat[0], heat[1], heat[2], heat[3]);
    *(float4*)(out + base + 1 * cs) = make_float4(dx, dx, dx, dx);
    *(float4*)(out + base + 2 * cs) = make_float4(dy, dy, dy, dy);
    *(float4*)(out + base + 3 * cs) = make_float4(v[0][0], v[0][1], v[0][2], v[0][3]);
    *(float4*)(out + base + 4 * cs) = make_float4(v[1][0], v[1][1], v[1][2], v[1][3]);
    *(float4*)(out + base + 5 * cs) = make_float4(v[2][0], v[2][1], v[2][2], v[2][3]);
}

extern "C" void kernel_launch(void* const* d_in, const int* in_sizes, int n_in,
                              void* d_out, int out_size, void* d_ws, size_t ws_size,
                              hipStream_t stream) {
    const float* src = (const float*)d_in[0];   // (4,3,1,128,128)
    const float* kpd = (const float*)d_in[1];   // (4,8,10,2)
    const float* kps = (const float*)d_in[2];   // (4,8,10,2)
    float* out  = (float*)d_out;                // (4,66,8,128,128)
    float* norm = (float*)d_ws;                 // 320 floats

    memb_norm_kernel<<<BS * D * K, 64, 0, stream>>>(kpd, norm);

    // 4 px/thread: grid.x covers HW, grid.y covers (b,d,k) slots.
    dim3 grid(HW / (256 * 4), BS * D * K1);
    memb_main_kernel<<<grid, 256, 0, stream>>>(src, kpd, kps, norm, out);
}